// Round 9
// baseline (201.456 us; speedup 1.0000x reference)
//
#include <hip/hip_runtime.h>
#include <hip/hip_bf16.h>
#include <climits>

#define B_ 2
#define V_ 4
#define H_ 120
#define W_ 160
#define C_ 96
#define NVOX 200000
#define GRID_ 128
#define NSTEPS 156
#define NRAYS (B_*V_*H_*W_)       // 153600
#define NB1 ((NVOX + 255) / 256)  // 782 blocks over voxels
#define CHUNK 16                  // rays per wave in scatter (was 64)
#define OUTQ2 ((NVOX * C_) / 4)   // 4,800,000 float4s: out rows
#define NTHREADS_MARCH (2400 * 256)

// NOTE (round-8 post-mortem): slab window null — misses are OCCUPANCY misses
// (rays traverse the grid, windows stay wide). Accounting: data movement
// ~140MB ~= 25us, VALU ~19us (r4 fused profile), measured 190us => LATENCY-
// bound. This round attacks the two dependent-load chains:
//   march: early-exit break serialized 5 mask-load rounds -> 2-deep software
//          pipeline (issue batch k+1 loads BEFORE evaluating batch k), static
//          double-buffered arrays, early exit kept. same[]-dedup dropped
//          (direction ~ +z: every step is a different mask word).
//   scatter: 600 blocks = 2.3/CU under-occupied + 8 serial load groups ->
//          CHUNK 16 (9600 waves, 2400 blocks) + ALL 16 row loads pre-issued.

// ------- Kernel A: occ id grid + 64-bit occupancy bitmask -------------------
// occ NOT pre-initialized (mask gates all reads). Raw coords: the reference's
// per-batch shift is a provable no-op (integer s => floor(pw-s)=floor(pw)-s).
__global__ void occ_kernel(const int* __restrict__ coords,
                           int* __restrict__ occ,
                           unsigned long long* __restrict__ mask) {
    int i = blockIdx.x * blockDim.x + threadIdx.x;
    if (i >= NVOX) return;
    int b = coords[i * 4 + 0];
    int x = coords[i * 4 + 1];
    int y = coords[i * 4 + 2];
    int z = coords[i * 4 + 3];
    int idx = ((b * GRID_ + z) * GRID_ + y) * GRID_ + x;
    atomicMax(&occ[idx], i);        // last-dup wins == max ray id
    atomicOr(&mask[idx >> 6], 1ull << (idx & 63));
}

// ---- march helper macros: compute batch / issue loads / evaluate batch -----
#define MARCH_COMPUTE(LIN, OK, W0)                                          \
    _Pragma("unroll")                                                       \
    for (int j = 0; j < 8; ++j) {                                           \
        int st = (W0) + sub * 8 + j;                                        \
        float t = 2.0f + 0.5f * (float)st;                                  \
        int ix = (int)floorf(d0 * t + t0);                                  \
        int iy = (int)floorf(d1 * t + t1);                                  \
        int iz = (int)floorf(d2 * t + t2);                                  \
        OK[j] = ((unsigned)ix < (unsigned)GRID_) &                          \
                ((unsigned)iy < (unsigned)GRID_) &                          \
                ((unsigned)iz < (unsigned)GRID_) & (st < NSTEPS);           \
        int cix = min(max(ix, 0), GRID_ - 1);                               \
        int ciy = min(max(iy, 0), GRID_ - 1);                               \
        int ciz = min(max(iz, 0), GRID_ - 1);                               \
        LIN[j] = vbase + (ciz << 14) + (ciy << 7) + cix;                    \
    }

#define MARCH_LOAD(U, LIN)                                                  \
    _Pragma("unroll")                                                       \
    for (int j = 0; j < 8; ++j) U[j] = mask[LIN[j] >> 6];

#define MARCH_EVAL(U, LIN, OK, W0)                                          \
    {                                                                       \
        int local = MISS;                                                   \
        _Pragma("unroll")                                                   \
        for (int j = 0; j < 8; ++j) {                                       \
            int st = (W0) + sub * 8 + j;                                    \
            if (OK[j] && ((U[j] >> (LIN[j] & 63)) & 1ull))                  \
                local = min(local, st);                                     \
        }                                                                   \
        local = min(local, __shfl_xor(local, 16));                          \
        local = min(local, __shfl_xor(local, 32));                          \
        if (local != MISS) { beststep = local; goto resolved; }             \
    }

// -------- Kernel B: pipelined march + wave cnt + d_out zero tail ------------
// Wave = 16 consecutive pixels x 4 step-subgroups x 8 steps = 32 steps/batch,
// 5 batches (steps 0..155). Batch k+1's mask loads are in flight while batch
// k is evaluated; early exit preserved (one extra batch wasted on hit).
__global__ void march_kernel(const float* __restrict__ vm,
                             const float* __restrict__ intr,
                             const unsigned long long* __restrict__ mask,
                             const int* __restrict__ occ,
                             int* __restrict__ tgt,
                             int* __restrict__ cnt,
                             float* __restrict__ out) {
    int gt   = blockIdx.x * blockDim.x + threadIdx.x;
    int lane = threadIdx.x & 63;
    int p    = lane & 15;
    int sub  = lane >> 4;
    int r    = ((gt >> 6) << 4) + p;   // grid exactly covers NRAYS
    {
        int w = r % W_;
        int h = (r / W_) % H_;
        int v = (r / (W_ * H_)) % V_;
        int b = r / (W_ * H_ * V_);
        const float* M = vm + (size_t)(b * V_ + v) * 16;
        float fx = intr[0], fy = intr[1], cx = intr[2], cy = intr[3];
        float dx = ((float)w + 0.5f - cx) / fx;
        float dy = ((float)h + 0.5f - cy) / fy;
        // d = R * (dx, dy, 1); t = raw translation (no shift)
        float d0 = M[0] * dx + M[1] * dy + M[2];
        float d1 = M[4] * dx + M[5] * dy + M[6];
        float d2 = M[8] * dx + M[9] * dy + M[10];
        float t0 = M[3];
        float t1 = M[7];
        float t2 = M[11];
        const int vbase = b * GRID_ * GRID_ * GRID_;
        const int MISS = 0x7FFFFFFF;
        int beststep = MISS;
        int res = -1;                       // declared before goto targets
        int linA[8], linB[8];
        bool okA[8], okB[8];
        unsigned long long uA[8], uB[8];
        // 2-deep pipeline over 5 batches: w0 = 0,32,64,96,128
        MARCH_COMPUTE(linA, okA, 0)   MARCH_LOAD(uA, linA)
        MARCH_COMPUTE(linB, okB, 32)  MARCH_LOAD(uB, linB)
        MARCH_EVAL(uA, linA, okA, 0)
        MARCH_COMPUTE(linA, okA, 64)  MARCH_LOAD(uA, linA)
        MARCH_EVAL(uB, linB, okB, 32)
        MARCH_COMPUTE(linB, okB, 96)  MARCH_LOAD(uB, linB)
        MARCH_EVAL(uA, linA, okA, 64)
        MARCH_COMPUTE(linA, okA, 128) MARCH_LOAD(uA, linA)
        MARCH_EVAL(uB, linB, okB, 96)
        MARCH_EVAL(uA, linA, okA, 128)
resolved:
        // resolve first-hit id (only the 16 result lanes read occ)
        if (sub == 0) {
            if (beststep != MISS) {
                float t = 2.0f + 0.5f * (float)beststep;
                int ix = (int)floorf(d0 * t + t0);
                int iy = (int)floorf(d1 * t + t1);
                int iz = (int)floorf(d2 * t + t2);
                res = occ[vbase + (iz << 14) + (iy << 7) + ix];
            }
            tgt[r] = res;
        }
        // wave-aggregated histogram: one atomic per contiguous equal-target run
        bool active = (sub == 0) && (res >= 0);
        int prevres = __shfl_up(res, 1);
        bool head = active && (p == 0 || prevres != res);
        bool boundary = head || !active;
        unsigned long long bb = __ballot(boundary);
        if (head) {
            unsigned long long above = bb & ~((2ull << lane) - 1);  // boundaries > lane
            int next = above ? (__ffsll((long long)above) - 1) : 64;
            atomicAdd(&cnt[res], next - lane);                      // run length
        }
    }
    // ---- folded zero of the out-row region (76.8 MB): latency-bound kernel,
    // stores ride idle BW; consumed by scatter, 1 boundary downstream. -------
    float4 z4 = make_float4(0.f, 0.f, 0.f, 0.f);
    float4* o4 = (float4*)out;
    for (int i = gt; i < OUTQ2; i += NTHREADS_MARCH) o4[i] = z4;
}

// ---------------- run flush: pre-divided atomic accumulate ------------------
__device__ __forceinline__ void flush_run(int t, float ax, float ay, int lane,
                                          const int* __restrict__ cnt,
                                          float* __restrict__ out) {
    float denom = (float)cnt[t] + 0.0001f;   // same addr all lanes: broadcast
    if (lane < 48) {
        unsafeAtomicAdd(out + (size_t)t * C_ + 2 * lane,     ax / denom);
        unsafeAtomicAdd(out + (size_t)t * C_ + 2 * lane + 1, ay / denom);
    }
}

// ---------------- Kernel C: ray-order scatter, all loads pre-issued ---------
// Wave = CHUNK=16 consecutive rays (9600 waves = 4x the old parallelism);
// lane<48 = channel pair. All 16 feats rows issued up-front (one latency
// round), then run-aggregated flushes pre-divided by cnt[t]+1e-4.
__global__ void scatter_kernel(const float* __restrict__ feats,
                               const int* __restrict__ tgt,
                               const int* __restrict__ cnt,
                               float* __restrict__ out,
                               float* __restrict__ cnt_out) {
    int gthread = blockIdx.x * blockDim.x + threadIdx.x;
    int lane = threadIdx.x & 63;
    if (gthread < NVOX) cnt_out[gthread] = (float)cnt[gthread];  // grid >= NVOX
    int wave = gthread >> 6;
    int a = wave * CHUNK;                 // grid sized exactly: a < NRAYS
    int myt = (lane < CHUNK) ? tgt[a + lane] : -1;
    float2 vbuf[CHUNK]; int tt[CHUNK];
#pragma unroll
    for (int k = 0; k < CHUNK; ++k) {     // issue ALL 16 row loads
        tt[k] = __shfl(myt, k);
        vbuf[k] = make_float2(0.0f, 0.0f);
        if (tt[k] >= 0 && lane < 48)
            vbuf[k] = ((const float2*)(feats + (size_t)(a + k) * C_))[lane];
    }
    float ax = 0.0f, ay = 0.0f;
    int cur = -1;
#pragma unroll
    for (int k = 0; k < CHUNK; ++k) {
        if (tt[k] != cur) {
            if (cur >= 0) flush_run(cur, ax, ay, lane, cnt, out);
            cur = tt[k]; ax = 0.0f; ay = 0.0f;
        }
        ax += vbuf[k].x; ay += vbuf[k].y;
    }
    if (cur >= 0) flush_run(cur, ax, ay, lane, cnt, out);
}

extern "C" void kernel_launch(void* const* d_in, const int* in_sizes, int n_in,
                              void* d_out, int out_size, void* d_ws, size_t ws_size,
                              hipStream_t stream) {
    const float* feats  = (const float*)d_in[0];
    const int*   coords = (const int*)d_in[1];
    const float* vm     = (const float*)d_in[2];
    const float* intr   = (const float*)d_in[3];

    float* out     = (float*)d_out;                  // NVOX*C_ floats
    float* cnt_out = out + (size_t)NVOX * C_;        // NVOX floats

    char* ws = (char*)d_ws;
    // zero region (one 1.3MB memset): [unused 64B] | cnt | mask
    int*                cnt  = (int*)(ws + 64);              // 800,000 B
    unsigned long long* mask = (unsigned long long*)(ws + 800064); // 524,288 B -> ends 1,324,352
    int*  tgt = (int*)(ws + 1324416);                        // 614,400 B
    int*  occ = (int*)(ws + 4786816);                        // 33,554,432 B (mask-gated)

    (void)hipMemsetAsync(ws, 0, 1324352, stream);

    occ_kernel<<<NB1, 256, 0, stream>>>(coords, occ, mask);
    march_kernel<<<2400, 256, 0, stream>>>(vm, intr, mask, occ, tgt, cnt, out);
    scatter_kernel<<<NRAYS * 4 / 256, 256, 0, stream>>>(feats, tgt, cnt, out, cnt_out);
}

// Round 10
// 187.693 us; speedup vs baseline: 1.0733x; 1.0733x over previous
//
#include <hip/hip_runtime.h>
#include <hip/hip_bf16.h>
#include <climits>

#define B_ 2
#define V_ 4
#define H_ 120
#define W_ 160
#define C_ 96
#define NVOX 200000
#define GRID_ 128
#define NSTEPS 156
#define NRAYS (B_*V_*H_*W_)       // 153600
#define NB1 ((NVOX + 255) / 256)  // 782 blocks over voxels
#define CHUNK 64                  // rays per wave in scatter (16 regressed: 4x flushes)
#define OUTQ2 ((NVOX * C_) / 4)   // 4,800,000 float4s: out rows
#define NTHREADS_MARCH (2400 * 256)

// NOTE (round-9 post-mortem): scatter surfaced at 55us, 15% HBM, VALU 7% —
// atomic-RMW bound; CHUNK 16 quadrupled boundary-split flushes (96 scalar
// f32 RMWs each) => regression. This round: CHUNK back to 64 AND complete-run
// plain stores: when runlen == cnt[t], the run is provably the voxel's entire
// contribution (two disjoint runs of length c would need 2c>c rays), so one
// plain float2 store replaces 96 atomics. Atomics remain only for boundary-
// clipped runs and multi-view voxels. Removes the RMW fetch-back of rows
// march's tail just zeroed.

// ------- Kernel A: occ id grid + 64-bit occupancy bitmask -------------------
// occ NOT pre-initialized (mask gates all reads). Raw coords: the reference's
// per-batch shift is a provable no-op (integer s => floor(pw-s)=floor(pw)-s).
__global__ void occ_kernel(const int* __restrict__ coords,
                           int* __restrict__ occ,
                           unsigned long long* __restrict__ mask) {
    int i = blockIdx.x * blockDim.x + threadIdx.x;
    if (i >= NVOX) return;
    int b = coords[i * 4 + 0];
    int x = coords[i * 4 + 1];
    int y = coords[i * 4 + 2];
    int z = coords[i * 4 + 3];
    int idx = ((b * GRID_ + z) * GRID_ + y) * GRID_ + x;
    atomicMax(&occ[idx], i);        // last-dup wins == max ray id
    atomicOr(&mask[idx >> 6], 1ull << (idx & 63));
}

// ---- march helper macros: compute batch / issue loads / evaluate batch -----
#define MARCH_COMPUTE(LIN, OK, W0)                                          \
    _Pragma("unroll")                                                       \
    for (int j = 0; j < 8; ++j) {                                           \
        int st = (W0) + sub * 8 + j;                                        \
        float t = 2.0f + 0.5f * (float)st;                                  \
        int ix = (int)floorf(d0 * t + t0);                                  \
        int iy = (int)floorf(d1 * t + t1);                                  \
        int iz = (int)floorf(d2 * t + t2);                                  \
        OK[j] = ((unsigned)ix < (unsigned)GRID_) &                          \
                ((unsigned)iy < (unsigned)GRID_) &                          \
                ((unsigned)iz < (unsigned)GRID_) & (st < NSTEPS);           \
        int cix = min(max(ix, 0), GRID_ - 1);                               \
        int ciy = min(max(iy, 0), GRID_ - 1);                               \
        int ciz = min(max(iz, 0), GRID_ - 1);                               \
        LIN[j] = vbase + (ciz << 14) + (ciy << 7) + cix;                    \
    }

#define MARCH_LOAD(U, LIN)                                                  \
    _Pragma("unroll")                                                       \
    for (int j = 0; j < 8; ++j) U[j] = mask[LIN[j] >> 6];

#define MARCH_EVAL(U, LIN, OK, W0)                                          \
    {                                                                       \
        int local = MISS;                                                   \
        _Pragma("unroll")                                                   \
        for (int j = 0; j < 8; ++j) {                                       \
            int st = (W0) + sub * 8 + j;                                    \
            if (OK[j] && ((U[j] >> (LIN[j] & 63)) & 1ull))                  \
                local = min(local, st);                                     \
        }                                                                   \
        local = min(local, __shfl_xor(local, 16));                          \
        local = min(local, __shfl_xor(local, 32));                          \
        if (local != MISS) { beststep = local; goto resolved; }             \
    }

// -------- Kernel B: pipelined march + wave cnt + d_out zero tail ------------
// Wave = 16 consecutive pixels x 4 step-subgroups x 8 steps = 32 steps/batch,
// 5 batches (steps 0..155). Batch k+1's mask loads are in flight while batch
// k is evaluated; early exit preserved (one extra batch wasted on hit).
__global__ void march_kernel(const float* __restrict__ vm,
                             const float* __restrict__ intr,
                             const unsigned long long* __restrict__ mask,
                             const int* __restrict__ occ,
                             int* __restrict__ tgt,
                             int* __restrict__ cnt,
                             float* __restrict__ out) {
    int gt   = blockIdx.x * blockDim.x + threadIdx.x;
    int lane = threadIdx.x & 63;
    int p    = lane & 15;
    int sub  = lane >> 4;
    int r    = ((gt >> 6) << 4) + p;   // grid exactly covers NRAYS
    {
        int w = r % W_;
        int h = (r / W_) % H_;
        int v = (r / (W_ * H_)) % V_;
        int b = r / (W_ * H_ * V_);
        const float* M = vm + (size_t)(b * V_ + v) * 16;
        float fx = intr[0], fy = intr[1], cx = intr[2], cy = intr[3];
        float dx = ((float)w + 0.5f - cx) / fx;
        float dy = ((float)h + 0.5f - cy) / fy;
        // d = R * (dx, dy, 1); t = raw translation (no shift)
        float d0 = M[0] * dx + M[1] * dy + M[2];
        float d1 = M[4] * dx + M[5] * dy + M[6];
        float d2 = M[8] * dx + M[9] * dy + M[10];
        float t0 = M[3];
        float t1 = M[7];
        float t2 = M[11];
        const int vbase = b * GRID_ * GRID_ * GRID_;
        const int MISS = 0x7FFFFFFF;
        int beststep = MISS;
        int res = -1;                       // declared before goto targets
        int linA[8], linB[8];
        bool okA[8], okB[8];
        unsigned long long uA[8], uB[8];
        // 2-deep pipeline over 5 batches: w0 = 0,32,64,96,128
        MARCH_COMPUTE(linA, okA, 0)   MARCH_LOAD(uA, linA)
        MARCH_COMPUTE(linB, okB, 32)  MARCH_LOAD(uB, linB)
        MARCH_EVAL(uA, linA, okA, 0)
        MARCH_COMPUTE(linA, okA, 64)  MARCH_LOAD(uA, linA)
        MARCH_EVAL(uB, linB, okB, 32)
        MARCH_COMPUTE(linB, okB, 96)  MARCH_LOAD(uB, linB)
        MARCH_EVAL(uA, linA, okA, 64)
        MARCH_COMPUTE(linA, okA, 128) MARCH_LOAD(uA, linA)
        MARCH_EVAL(uB, linB, okB, 96)
        MARCH_EVAL(uA, linA, okA, 128)
resolved:
        // resolve first-hit id (only the 16 result lanes read occ)
        if (sub == 0) {
            if (beststep != MISS) {
                float t = 2.0f + 0.5f * (float)beststep;
                int ix = (int)floorf(d0 * t + t0);
                int iy = (int)floorf(d1 * t + t1);
                int iz = (int)floorf(d2 * t + t2);
                res = occ[vbase + (iz << 14) + (iy << 7) + ix];
            }
            tgt[r] = res;
        }
        // wave-aggregated histogram: one atomic per contiguous equal-target run
        bool active = (sub == 0) && (res >= 0);
        int prevres = __shfl_up(res, 1);
        bool head = active && (p == 0 || prevres != res);
        bool boundary = head || !active;
        unsigned long long bb = __ballot(boundary);
        if (head) {
            unsigned long long above = bb & ~((2ull << lane) - 1);  // boundaries > lane
            int next = above ? (__ffsll((long long)above) - 1) : 64;
            atomicAdd(&cnt[res], next - lane);                      // run length
        }
    }
    // ---- folded zero of the out-row region (76.8 MB): latency-bound kernel,
    // stores ride idle BW; consumed by scatter, 1 boundary downstream. -------
    float4 z4 = make_float4(0.f, 0.f, 0.f, 0.f);
    float4* o4 = (float4*)out;
    for (int i = gt; i < OUTQ2; i += NTHREADS_MARCH) o4[i] = z4;
}

// ---------- run flush: complete-run plain store / else atomic add -----------
// runlen == cnt[t] proves this run is the voxel's ENTIRE contribution (two
// disjoint runs of length c would need 2c > c rays): plain store, no RMW.
__device__ __forceinline__ void flush_run(int t, int runlen, float ax, float ay,
                                          int lane,
                                          const int* __restrict__ cnt,
                                          float* __restrict__ out) {
    int c = cnt[t];                          // same addr all lanes: broadcast
    float denom = (float)c + 0.0001f;
    if (runlen == c) {
        if (lane < 48) {
            float2 wv; wv.x = ax / denom; wv.y = ay / denom;
            ((float2*)(out + (size_t)t * C_))[lane] = wv;
        }
    } else if (lane < 48) {
        unsafeAtomicAdd(out + (size_t)t * C_ + 2 * lane,     ax / denom);
        unsafeAtomicAdd(out + (size_t)t * C_ + 2 * lane + 1, ay / denom);
    }
}

// ---------------- Kernel C: ray-order scatter (8-deep pipeline) -------------
// Wave = CHUNK=64 consecutive rays; lane<48 = channel pair. feats rows stream
// SEQUENTIALLY. Runs of equal tgt are summed in registers; flush is ONE plain
// store (complete run) or one pair of atomics (clipped / multi-view run).
__global__ void scatter_kernel(const float* __restrict__ feats,
                               const int* __restrict__ tgt,
                               const int* __restrict__ cnt,
                               float* __restrict__ out,
                               float* __restrict__ cnt_out) {
    int gthread = blockIdx.x * blockDim.x + threadIdx.x;
    int lane = threadIdx.x & 63;
    for (int i = gthread; i < NVOX; i += NRAYS)      // total threads = NRAYS/CHUNK*64
        cnt_out[i] = (float)cnt[i];
    int wave = gthread >> 6;
    int a = wave * CHUNK;                 // grid sized exactly: a < NRAYS
    int myt = tgt[a + lane];              // 64 rays per wave
    float ax = 0.0f, ay = 0.0f;
    int cur = -1, rstart = 0;
    for (int k0 = 0; k0 < CHUNK; k0 += 8) {
        float2 vbuf[8]; int tt[8];
#pragma unroll
        for (int j = 0; j < 8; ++j) {             // issue 8 sequential row loads
            int k = k0 + j;
            tt[j] = __shfl(myt, k);
            vbuf[j] = make_float2(0.0f, 0.0f);
            if (tt[j] >= 0 && lane < 48)
                vbuf[j] = ((const float2*)(feats + (size_t)(a + k) * C_))[lane];
        }
#pragma unroll
        for (int j = 0; j < 8; ++j) {
            int k = k0 + j;
            if (tt[j] != cur) {
                if (cur >= 0) flush_run(cur, k - rstart, ax, ay, lane, cnt, out);
                cur = tt[j]; rstart = k; ax = 0.0f; ay = 0.0f;
            }
            ax += vbuf[j].x; ay += vbuf[j].y;
        }
    }
    if (cur >= 0) flush_run(cur, CHUNK - rstart, ax, ay, lane, cnt, out);
}

extern "C" void kernel_launch(void* const* d_in, const int* in_sizes, int n_in,
                              void* d_out, int out_size, void* d_ws, size_t ws_size,
                              hipStream_t stream) {
    const float* feats  = (const float*)d_in[0];
    const int*   coords = (const int*)d_in[1];
    const float* vm     = (const float*)d_in[2];
    const float* intr   = (const float*)d_in[3];

    float* out     = (float*)d_out;                  // NVOX*C_ floats
    float* cnt_out = out + (size_t)NVOX * C_;        // NVOX floats

    char* ws = (char*)d_ws;
    // zero region (one 1.3MB memset): [unused 64B] | cnt | mask
    int*                cnt  = (int*)(ws + 64);              // 800,000 B
    unsigned long long* mask = (unsigned long long*)(ws + 800064); // 524,288 B -> ends 1,324,352
    int*  tgt = (int*)(ws + 1324416);                        // 614,400 B
    int*  occ = (int*)(ws + 4786816);                        // 33,554,432 B (mask-gated)

    (void)hipMemsetAsync(ws, 0, 1324352, stream);

    occ_kernel<<<NB1, 256, 0, stream>>>(coords, occ, mask);
    march_kernel<<<2400, 256, 0, stream>>>(vm, intr, mask, occ, tgt, cnt, out);
    scatter_kernel<<<NRAYS / 256, 256, 0, stream>>>(feats, tgt, cnt, out, cnt_out);
}